// Round 1
// baseline (83.426 us; speedup 1.0000x reference)
//
#include <hip/hip_runtime.h>
#include <cfloat>

#define N_ELEM (1 << 20)
#define K_CENTERS 256
#define EPT 8          // elements per thread
#define BLOCK 256

__global__ __launch_bounds__(BLOCK) void kmeans_argmin_brute(
    const float* __restrict__ x,
    const float* __restrict__ centers,
    int* __restrict__ out)
{
    const int base = (blockIdx.x * BLOCK + threadIdx.x) * EPT;

    // 8 contiguous elements per thread via two float4 loads (coalesced, 16B/lane)
    float4 a = *reinterpret_cast<const float4*>(x + base);
    float4 b = *reinterpret_cast<const float4*>(x + base + 4);
    float xs[EPT] = {a.x, a.y, a.z, a.w, b.x, b.y, b.z, b.w};

    float bd[EPT];
    int   bi[EPT];
#pragma unroll
    for (int e = 0; e < EPT; ++e) { bd[e] = FLT_MAX; bi[e] = 0; }

    // centers[k] is wave-uniform -> scalar loads (s_load), center sits in SGPR
#pragma unroll 16
    for (int k = 0; k < K_CENTERS; ++k) {
        const float c = centers[k];
#pragma unroll
        for (int e = 0; e < EPT; ++e) {
            float d = fabsf(xs[e] - c);
            if (d < bd[e]) { bd[e] = d; bi[e] = k; }  // strict < => first-occurrence argmin
        }
    }

    *reinterpret_cast<int4*>(out + base)     = make_int4(bi[0], bi[1], bi[2], bi[3]);
    *reinterpret_cast<int4*>(out + base + 4) = make_int4(bi[4], bi[5], bi[6], bi[7]);
}

extern "C" void kernel_launch(void* const* d_in, const int* in_sizes, int n_in,
                              void* d_out, int out_size, void* d_ws, size_t ws_size,
                              hipStream_t stream)
{
    const float* x       = (const float*)d_in[0];
    const float* centers = (const float*)d_in[1];
    int*         out     = (int*)d_out;

    const int grid = N_ELEM / (BLOCK * EPT);  // 512 blocks
    kmeans_argmin_brute<<<grid, BLOCK, 0, stream>>>(x, centers, out);
}

// Round 2
// 67.617 us; speedup vs baseline: 1.2338x; 1.2338x over previous
//
#include <hip/hip_runtime.h>

#define N_ELEM (1 << 20)
#define K 256
#define BLOCK 256
#define EPT 4
#define GRID (N_ELEM / (BLOCK * EPT))   // 1024 blocks -> 4 blocks/CU, 16 waves/CU

// d_ws layout: float sorted_val[256] | int sorted_orig_idx[256]

// Rank sort: thread t's center goes to slot rank(t). Stable: ties broken by
// original index, so duplicates (if any) keep ascending original order.
__global__ __launch_bounds__(K) void sort_centers_kernel(
    const float* __restrict__ centers,
    float* __restrict__ ws_val,
    int*   __restrict__ ws_idx)
{
    __shared__ float sc[K];
    const int t = threadIdx.x;
    const float c = centers[t];
    sc[t] = c;
    __syncthreads();

    int rank = 0;
#pragma unroll 8
    for (int j = 0; j < K; ++j) {
        float cj = sc[j];
        rank += (cj < c) || (cj == c && j < t);
    }
    ws_val[rank] = c;
    ws_idx[rank] = t;
}

__global__ __launch_bounds__(BLOCK) void argmin_bsearch_kernel(
    const float* __restrict__ x,
    const float* __restrict__ ws_val,
    const int*   __restrict__ ws_idx,
    int*         __restrict__ out)
{
    __shared__ float s_val[K];
    __shared__ int   s_idx[K];
    const int t = threadIdx.x;
    s_val[t] = ws_val[t];
    s_idx[t] = ws_idx[t];
    __syncthreads();

    const int base = (blockIdx.x * BLOCK + t) * EPT;
    float4 v = *reinterpret_cast<const float4*>(x + base);
    float xs[EPT] = {v.x, v.y, v.z, v.w};
    int res[EPT];

#pragma unroll
    for (int e = 0; e < EPT; ++e) {
        const float xv = xs[e];
        // branchless lower_bound: pos = #centers < xv, in [0,256]
        int pos = 0;
#pragma unroll
        for (int s = 128; s > 0; s >>= 1)
            pos += (s_val[pos + s - 1] < xv) ? s : 0;   // pos <= 255 after loop
        pos += (s_val[pos] < xv) ? 1 : 0;

        // nearest is one of the two straddling neighbors (fp32 distances are
        // weakly unimodal over sorted centers); exact tie -> smaller orig idx
        const int il = (pos > 0)  ? pos - 1 : 0;
        const int ir = (pos < K)  ? pos     : K - 1;
        const float dl = fabsf(xv - s_val[il]);
        const float dr = fabsf(xv - s_val[ir]);
        const int ol = s_idx[il], orr = s_idx[ir];
        res[e] = (dl < dr) ? ol : ((dr < dl) ? orr : min(ol, orr));
    }

    *reinterpret_cast<int4*>(out + base) = make_int4(res[0], res[1], res[2], res[3]);
}

extern "C" void kernel_launch(void* const* d_in, const int* in_sizes, int n_in,
                              void* d_out, int out_size, void* d_ws, size_t ws_size,
                              hipStream_t stream)
{
    const float* x       = (const float*)d_in[0];
    const float* centers = (const float*)d_in[1];
    int*         out     = (int*)d_out;

    float* ws_val = (float*)d_ws;
    int*   ws_idx = (int*)(ws_val + K);

    sort_centers_kernel<<<1, K, 0, stream>>>(centers, ws_val, ws_idx);
    argmin_bsearch_kernel<<<GRID, BLOCK, 0, stream>>>(x, ws_val, ws_idx, out);
}